// Round 6
// baseline (768.411 us; speedup 1.0000x reference)
//
#include <hip/hip_runtime.h>
#include <hip/hip_bf16.h>
#include <cstdint>
#include <cstddef>

typedef __bf16 bf16;
typedef __attribute__((ext_vector_type(4))) __bf16 bf16x4;
typedef __attribute__((ext_vector_type(8))) __bf16 bf16x8;
typedef __attribute__((ext_vector_type(4))) float f32x4;

#define NR 8192      // B*S rows
#define DIM_D 1024
#define DIM_H 4096

// ---------------------------------------------------------------- helpers

__device__ __forceinline__ void gload_lds16(const void* g, void* l) {
  __builtin_amdgcn_global_load_lds(
      (const __attribute__((address_space(1))) void*)g,
      (__attribute__((address_space(3))) void*)l, 16, 0, 0);
}

#define BAR()  __builtin_amdgcn_s_barrier()
#define WLG0() asm volatile("s_waitcnt lgkmcnt(0)" ::: "memory")
#define WVM0() asm volatile("s_waitcnt vmcnt(0)" ::: "memory")
#define WVM4() asm volatile("s_waitcnt vmcnt(4)" ::: "memory")
#define WVM6() asm volatile("s_waitcnt vmcnt(6)" ::: "memory")
#define WVM8() asm volatile("s_waitcnt vmcnt(8)" ::: "memory")
#define PRIO1() __builtin_amdgcn_s_setprio(1)
#define PRIO0() __builtin_amdgcn_s_setprio(0)

// ---------------------------------------------------------------- prep kernels

// Coalesced permuted-B prep. Block = (256 outputs) x (32 inputs = 1 chunk).
// Tile kt = chunk*2 + dp (dp=(k-1)>>1); elem (dh*4+q)*2048 + r*8 + j, dh=(k-1)&1,
// input i = chunk*32 + q*8 + j, r = o&255. bpart[chunk][o] = sum_i coef[i][o][0].
template <int IN, int OUT>
__global__ __launch_bounds__(256) void k_prep_t(const float* __restrict__ coef,
                                                bf16* __restrict__ Bp,
                                                float* __restrict__ bpart) {
  constexpr int KT = (IN / 32) * 2;
  const int tid   = threadIdx.x;
  const int o     = blockIdx.x * 256 + tid;
  const int nb    = blockIdx.x;
  const int chunk = blockIdx.y;
  const int i0    = chunk * 32;

  float bacc = 0.f;
#pragma unroll
  for (int q = 0; q < 4; ++q) {
    bf16x8 w1, w2, w3, w4;
#pragma unroll
    for (int j = 0; j < 8; ++j) {
      const float* s = coef + ((size_t)(i0 + q * 8 + j) * OUT + o) * 5;
      bacc += s[0];
      w1[j] = (bf16)s[1]; w2[j] = (bf16)s[2]; w3[j] = (bf16)s[3]; w4[j] = (bf16)s[4];
    }
    bf16* base = Bp + ((size_t)nb * KT + chunk * 2) * 16384 + (size_t)tid * 8;
    *(bf16x8*)(base + (0 * 4 + q) * 2048)         = w1;
    *(bf16x8*)(base + (1 * 4 + q) * 2048)         = w2;
    *(bf16x8*)(base + 16384 + (0 * 4 + q) * 2048) = w3;
    *(bf16x8*)(base + 16384 + (1 * 4 + q) * 2048) = w4;
  }
  bpart[(size_t)chunk * OUT + o] = bacc;
}

__global__ __launch_bounds__(256) void k_bias_red(const float* __restrict__ bpart,
                                                  float* __restrict__ bias,
                                                  const int OUT, const int NP) {
  const int o = blockIdx.x * 256 + threadIdx.x;
  float s = 0.f;
  for (int p = 0; p < NP; ++p) s += bpart[(size_t)p * OUT + o];
  bias[o] = s;
}

// Ax[row][col'] = T_k(tanh(x[row][i])), col' = chunk*128 + (k-1)*32 + q*8 + j.
__global__ __launch_bounds__(256) void k_tanh_cheb(const float* __restrict__ x,
                                                   bf16* __restrict__ Ax) {
  const size_t base = ((size_t)blockIdx.x * 256 + threadIdx.x) * 8;
  const size_t row  = base >> 10;
  const int    i    = (int)(base & 1023);
  const float4 v0 = *(const float4*)(x + base);
  const float4 v1 = *(const float4*)(x + base + 4);
  float f[8] = {tanhf(v0.x), tanhf(v0.y), tanhf(v0.z), tanhf(v0.w),
                tanhf(v1.x), tanhf(v1.y), tanhf(v1.z), tanhf(v1.w)};
  bf16x8 w1, w2, w3, w4;
#pragma unroll
  for (int j = 0; j < 8; ++j) {
    const float a = f[j], a2 = a * a;
    w1[j] = (bf16)a;
    w2[j] = (bf16)(2.f * a2 - 1.f);
    w3[j] = (bf16)(a * (4.f * a2 - 3.f));
    w4[j] = (bf16)(8.f * a2 * (a2 - 1.f) + 1.f);
  }
  bf16* o = Ax + row * 4096 + (i >> 5) * 128 + ((i >> 3) & 3) * 8;
  *(bf16x8*)(o)      = w1;
  *(bf16x8*)(o + 32) = w2;
  *(bf16x8*)(o + 64) = w3;
  *(bf16x8*)(o + 96) = w4;
}

// PATH A: LayerNorm + tanh + cheb-expand, bf16 h row -> Ax2[row][16384].
__global__ __launch_bounds__(256) void k_lntanh_cheb(const bf16* __restrict__ h,
                                                     const float* __restrict__ gamma,
                                                     const float* __restrict__ beta,
                                                     bf16* __restrict__ Ax) {
  const int n = blockIdx.x;
  const int t = threadIdx.x;
  const bf16* row = h + (size_t)n * DIM_H;

  float v[16];
  float s1 = 0.f, s2 = 0.f;
  {
    const bf16x8 a = *(const bf16x8*)(row + t * 16);
    const bf16x8 b = *(const bf16x8*)(row + t * 16 + 8);
#pragma unroll
    for (int j = 0; j < 8; ++j) { v[j] = (float)a[j]; v[8 + j] = (float)b[j]; }
#pragma unroll
    for (int j = 0; j < 16; ++j) { s1 += v[j]; s2 += v[j] * v[j]; }
  }
#pragma unroll
  for (int off = 32; off >= 1; off >>= 1) {
    s1 += __shfl_xor(s1, off);
    s2 += __shfl_xor(s2, off);
  }
  __shared__ float red[8];
  if ((t & 63) == 0) { red[(t >> 6) * 2] = s1; red[(t >> 6) * 2 + 1] = s2; }
  __syncthreads();
  const float S1 = red[0] + red[2] + red[4] + red[6];
  const float S2 = red[1] + red[3] + red[5] + red[7];
  const float mu   = S1 * (1.f / DIM_H);
  const float var  = S2 * (1.f / DIM_H) - mu * mu;
  const float rstd = rsqrtf(var + 1e-5f);

  float f[16];
#pragma unroll
  for (int j = 0; j < 16; ++j) {
    const float g = gamma[t * 16 + j];
    const float b = beta[t * 16 + j];
    f[j] = tanhf((v[j] - mu) * rstd * g + b);
  }
  bf16* o = Ax + (size_t)n * 16384 + (t >> 1) * 128 + ((t & 1) * 2) * 8;
#pragma unroll
  for (int k = 1; k <= 4; ++k) {
    bf16x8 w0, w1;
#pragma unroll
    for (int j = 0; j < 8; ++j) {
      const float a = f[j], a2 = a * a;
      const float b = f[8 + j], b2 = b * b;
      float ra, rb;
      if (k == 1)      { ra = a;                           rb = b; }
      else if (k == 2) { ra = 2.f * a2 - 1.f;              rb = 2.f * b2 - 1.f; }
      else if (k == 3) { ra = a * (4.f * a2 - 3.f);        rb = b * (4.f * b2 - 3.f); }
      else             { ra = 8.f * a2 * (a2 - 1.f) + 1.f; rb = 8.f * b2 * (b2 - 1.f) + 1.f; }
      w0[j] = (bf16)ra; w1[j] = (bf16)rb;
    }
    *(bf16x8*)(o + (k - 1) * 32)     = w0;
    *(bf16x8*)(o + (k - 1) * 32 + 8) = w1;
  }
}

// PATH B: LayerNorm + tanh, fp32 h -> bf16 th (r5-proven numerics).
__global__ __launch_bounds__(256) void k_ln_tanh(const float* __restrict__ h,
                                                 const float* __restrict__ gamma,
                                                 const float* __restrict__ beta,
                                                 bf16* __restrict__ th) {
  const int n = blockIdx.x;
  const int t = threadIdx.x;
  const float* row = h + (size_t)n * DIM_H;

  float4 v[4];
  float s1 = 0.f, s2 = 0.f;
#pragma unroll
  for (int j = 0; j < 4; ++j) {
    v[j] = *(const float4*)(row + t * 16 + j * 4);
    s1 += v[j].x + v[j].y + v[j].z + v[j].w;
    s2 += v[j].x * v[j].x + v[j].y * v[j].y + v[j].z * v[j].z + v[j].w * v[j].w;
  }
#pragma unroll
  for (int off = 32; off >= 1; off >>= 1) {
    s1 += __shfl_xor(s1, off);
    s2 += __shfl_xor(s2, off);
  }
  __shared__ float red[8];
  if ((t & 63) == 0) { red[(t >> 6) * 2] = s1; red[(t >> 6) * 2 + 1] = s2; }
  __syncthreads();
  const float S1 = red[0] + red[2] + red[4] + red[6];
  const float S2 = red[1] + red[3] + red[5] + red[7];
  const float mu   = S1 * (1.f / DIM_H);
  const float var  = S2 * (1.f / DIM_H) - mu * mu;
  const float rstd = rsqrtf(var + 1e-5f);

  float tmp[16];
#pragma unroll
  for (int j = 0; j < 4; ++j) {
    const float4 g = *(const float4*)(gamma + t * 16 + j * 4);
    const float4 b = *(const float4*)(beta  + t * 16 + j * 4);
    tmp[j * 4 + 0] = tanhf((v[j].x - mu) * rstd * g.x + b.x);
    tmp[j * 4 + 1] = tanhf((v[j].y - mu) * rstd * g.y + b.y);
    tmp[j * 4 + 2] = tanhf((v[j].z - mu) * rstd * g.z + b.z);
    tmp[j * 4 + 3] = tanhf((v[j].w - mu) * rstd * g.w + b.w);
  }
  bf16x8 w0, w1;
#pragma unroll
  for (int j = 0; j < 8; ++j) { w0[j] = (bf16)tmp[j]; w1[j] = (bf16)tmp[8 + j]; }
  bf16* o = th + (size_t)n * DIM_H + t * 16;
  *(bf16x8*)o       = w0;
  *(bf16x8*)(o + 8) = w1;
}

// ---------------------------------------------------------------- pure 8-phase GEMM (m201)
// C = Ax * Bp^T (+bias). 256x256, BK=64, 8 waves (2Mx4N), dbuf 128KiB LDS.
// Both operands via global_load_lds; counted vmcnt(6) at P4/P8; A(buf1,kh1)
// staged in the NEXT group's P1 (deferred slot keeps 2 issues/phase).
template <int IND, int NZ, typename CT>
__global__ __launch_bounds__(512, 2) void k_gemm8x(const bf16* __restrict__ Ax,
                                                   const bf16* __restrict__ Bp,
                                                   CT* __restrict__ C,
                                                   const float* __restrict__ bias,
                                                   const int NN) {
  constexpr int KP  = IND * 4;             // expanded K'
  constexpr int NCH = IND / 32 / NZ;       // groups per z-slice
  constexpr int KTt = (IND / 32) * 2;      // 64-K tiles per n-block (total)

  __shared__ bf16 Ash[2][16384];
  __shared__ bf16 Bsh[2][16384];

  const int tid  = threadIdx.x;
  const int lane = tid & 63;
  const int wid  = tid >> 6;
  const int wm   = wid >> 2;
  const int wn   = wid & 3;
  const int fr   = lane & 15;
  const int kq   = lane >> 4;
  const int m0   = blockIdx.y * 256;
  const int n0   = blockIdx.x * 256;
  const int zc0  = blockIdx.z * NCH;

  f32x4 acc[8][4];
#pragma unroll
  for (int m = 0; m < 8; ++m)
#pragma unroll
    for (int n = 0; n < 4; ++n) acc[m][n] = (f32x4){0.f, 0.f, 0.f, 0.f};

  const size_t bt0 = (size_t)blockIdx.x * KTt + (size_t)zc0 * 2;
  const bf16* Az = Ax + (size_t)zc0 * 128;

  const int sub = tid >> 8;                // 0/1
  const int rA  = tid & 255;

  auto stB = [&](int d, int kh, int ktl) {
    const bf16* s = Bp + (bt0 + (size_t)ktl) * 16384 + kh * 8192 + tid * 8;
    bf16* l = &Bsh[d][kh * 8192 + tid * 8];
    gload_lds16(s, l);
    gload_lds16(s + 4096, l + 4096);
  };
  auto stA = [&](int d, int kh, int ktl) {
    const bf16* s = Az + (size_t)(m0 + rA) * KP + (size_t)ktl * 64 + kh * 32 + sub * 8;
    bf16* l = &Ash[d][(kh * 4 + sub) * 2048 + rA * 8];
    gload_lds16(s, l);
    gload_lds16(s + 16, l + 4096);         // +16 elems -> ksub+2
  };

  bf16x8 afr[4], bfr[4];
  auto rdB = [&](int d, int kh) {
#pragma unroll
    for (int n = 0; n < 4; ++n)
      bfr[n] = *(const bf16x8*)&Bsh[d][(kh * 4 + kq) * 2048 + (wn * 64 + n * 16 + fr) * 8];
  };
  auto rdA = [&](int d, int kh, int mh) {
#pragma unroll
    for (int m = 0; m < 4; ++m)
      afr[m] = *(const bf16x8*)&Ash[d][(kh * 4 + kq) * 2048 + (wm * 128 + mh * 64 + m * 16 + fr) * 8];
  };
  auto mma = [&](int mh) {
#pragma unroll
    for (int m = 0; m < 4; ++m)
#pragma unroll
      for (int n = 0; n < 4; ++n)
        acc[mh * 4 + m][n] =
            __builtin_amdgcn_mfma_f32_16x16x32_bf16(afr[m], bfr[n], acc[mh * 4 + m][n], 0, 0, 0);
  };

  // prologue: tiles 0 (buf0) and 1 (buf1); drain tile 0.
  stA(0, 0, 0); stA(0, 1, 0); stB(0, 0, 0); stB(0, 1, 0);
  stA(1, 0, 1); stA(1, 1, 1); stB(1, 0, 1); stB(1, 1, 1);
  WVM8();
  BAR();

#pragma unroll 1
  for (int g = 0; g < NCH; ++g) {
    const bool st = (g + 1 < NCH);
    // P1: deferred A(buf1,kh1) for tile 2g+1
    rdB(0, 0); rdA(0, 0, 0);
    if (g > 0) stA(1, 1, 2 * g + 1);
    BAR(); WLG0();
    PRIO1(); mma(0); PRIO0();
    BAR();
    // P2
    rdA(0, 0, 1);
    if (st) stB(0, 0, 2 * g + 2);
    BAR(); WLG0();
    PRIO1(); mma(1); PRIO0();
    BAR();
    // P3
    rdB(0, 1); rdA(0, 1, 0);
    if (st) stA(0, 0, 2 * g + 2);
    BAR(); WLG0();
    PRIO1(); mma(0); PRIO0();
    BAR();
    // P4: tile 2g+1 fully drained here
    rdA(0, 1, 1);
    if (st) { stB(0, 1, 2 * g + 2); WVM6(); } else { WVM0(); }
    BAR(); WLG0();
    PRIO1(); mma(1); PRIO0();
    BAR();
    // P5
    rdB(1, 0); rdA(1, 0, 0);
    if (st) stA(0, 1, 2 * g + 2);
    BAR(); WLG0();
    PRIO1(); mma(0); PRIO0();
    BAR();
    // P6
    rdA(1, 0, 1);
    if (st) stB(1, 0, 2 * g + 3);
    BAR(); WLG0();
    PRIO1(); mma(1); PRIO0();
    BAR();
    // P7
    rdB(1, 1); rdA(1, 1, 0);
    if (st) stA(1, 0, 2 * g + 3);
    BAR(); WLG0();
    PRIO1(); mma(0); PRIO0();
    BAR();
    // P8: tile 2g+2 fully drained here
    rdA(1, 1, 1);
    if (st) { stB(1, 1, 2 * g + 3); WVM6(); }
    BAR(); WLG0();
    PRIO1(); mma(1); PRIO0();
    BAR();
  }

  // epilogue
  float bv[4] = {0.f, 0.f, 0.f, 0.f};
  const int c0 = n0 + wn * 64 + fr;
  if (bias) {
#pragma unroll
    for (int n = 0; n < 4; ++n) bv[n] = bias[c0 + n * 16];
  }
  CT* Cz = C + (size_t)blockIdx.z * NR * NN;
  const int r0 = m0 + wm * 128 + kq * 4;
#pragma unroll
  for (int mi = 0; mi < 8; ++mi)
#pragma unroll
    for (int j = 0; j < 4; ++j) {
      CT* p = Cz + (size_t)(r0 + mi * 16 + j) * NN + c0;
#pragma unroll
      for (int n = 0; n < 4; ++n)
        p[n * 16] = (CT)(acc[mi][n][j] + bv[n]);
    }
}

// ---------------------------------------------------------------- fused GEMM (PATH B GEMM2)
template <int IND, int NZ>
__global__ __launch_bounds__(512, 2) void k_gemm8(const bf16* __restrict__ X,
                                                  const bf16* __restrict__ Bp,
                                                  float* __restrict__ C,
                                                  const float* __restrict__ bias,
                                                  const int NN) {
  constexpr int NCH = IND / 32 / NZ;
  constexpr int KTt = (IND / 32) * 2;

  __shared__ bf16 Ash[2][16384];
  __shared__ bf16 Bsh[2][16384];

  const int tid  = threadIdx.x;
  const int lane = tid & 63;
  const int wid  = tid >> 6;
  const int wm   = wid >> 2;
  const int wn   = wid & 3;
  const int fr   = lane & 15;
  const int kq   = lane >> 4;
  const int m0   = blockIdx.y * 256;
  const int n0   = blockIdx.x * 256;
  const int zc0  = blockIdx.z * NCH;

  const int ar = tid >> 1;
  const int aq = (tid & 1) * 2;

  f32x4 acc[8][4];
#pragma unroll
  for (int m = 0; m < 8; ++m)
#pragma unroll
    for (int n = 0; n < 4; ++n) acc[m][n] = (f32x4){0.f, 0.f, 0.f, 0.f};

  const bf16* xp = X + (size_t)(m0 + ar) * IND + (size_t)zc0 * 32 + aq * 8;
  const size_t bt0 = (size_t)blockIdx.x * KTt + (size_t)zc0 * 2;

  bf16x8 xn0, xn1;
  float  xf[16];
  bf16x8 afr[4], bfr[4];

  auto stB = [&](int d, int kh, int ktl) {
    const bf16* s = Bp + (bt0 + (size_t)ktl) * 16384 + kh * 8192 + tid * 8;
    bf16* l = &Bsh[d][kh * 8192 + tid * 8];
    gload_lds16(s, l);
    gload_lds16(s + 4096, l + 4096);
  };
  auto ldx = [&](int c) {
    const bf16* s = xp + (size_t)c * 32;
    xn0 = *(const bf16x8*)s;
    xn1 = *(const bf16x8*)(s + 8);
  };
  auto cvtxf = [&]() {
#pragma unroll
    for (int j = 0; j < 8; ++j) { xf[j] = (float)xn0[j]; xf[8 + j] = (float)xn1[j]; }
  };
  auto wA = [&](int d, int dh, bf16x8 w0, bf16x8 w1) {
    *(bf16x8*)&Ash[d][(dh * 4 + aq) * 2048 + ar * 8]       = w0;
    *(bf16x8*)&Ash[d][(dh * 4 + aq + 1) * 2048 + ar * 8]   = w1;
  };
  auto chebw = [&](int deg, bf16x8& w0, bf16x8& w1) {
#pragma unroll
    for (int j = 0; j < 8; ++j) {
      const float a = xf[j], b = xf[8 + j];
      const float a2 = a * a, b2 = b * b;
      float ra, rb;
      if (deg == 2)      { ra = 2.f * a2 - 1.f;            rb = 2.f * b2 - 1.f; }
      else if (deg == 3) { ra = a * (4.f * a2 - 3.f);      rb = b * (4.f * b2 - 3.f); }
      else               { ra = 8.f * a2 * (a2 - 1.f) + 1.f; rb = 8.f * b2 * (b2 - 1.f) + 1.f; }
      w0[j] = (bf16)ra; w1[j] = (bf16)rb;
    }
  };
  auto rdB = [&](int d, int kh) {
#pragma unroll
    for (int n = 0; n < 4; ++n)
      bfr[n] = *(const bf16x8*)&Bsh[d][(kh * 4 + kq) * 2048 + (wn * 64 + n * 16 + fr) * 8];
  };
  auto rdA = [&](int d, int kh, int mh) {
#pragma unroll
    for (int m = 0; m < 4; ++m)
      afr[m] = *(const bf16x8*)&Ash[d][(kh * 4 + kq) * 2048 + (wm * 128 + mh * 64 + m * 16 + fr) * 8];
  };
  auto mma = [&](int mh) {
#pragma unroll
    for (int m = 0; m < 4; ++m)
#pragma unroll
      for (int n = 0; n < 4; ++n)
        acc[mh * 4 + m][n] =
            __builtin_amdgcn_mfma_f32_16x16x32_bf16(afr[m], bfr[n], acc[mh * 4 + m][n], 0, 0, 0);
  };

  ldx(0);
  stB(0, 0, 0); stB(0, 1, 0);
  stB(1, 0, 1); stB(1, 1, 1);
  cvtxf();
  wA(0, 0, xn0, xn1);
  { bf16x8 w0, w1; chebw(2, w0, w1); wA(0, 1, w0, w1); }
  { bf16x8 w0, w1; chebw(3, w0, w1); wA(1, 0, w0, w1); }
  { bf16x8 w0, w1; chebw(4, w0, w1); wA(1, 1, w0, w1); }
  WVM0(); WLG0();
  BAR();

#pragma unroll 1
  for (int g = 0; g < NCH; ++g) {
    const bool st = (g + 1 < NCH);
    rdB(0, 0); rdA(0, 0, 0);
    if (g > 0) { bf16x8 w0, w1; chebw(4, w0, w1); wA(1, 1, w0, w1); }
    if (st) ldx(g + 1);
    BAR(); WLG0();
    PRIO1(); mma(0); PRIO0();
    BAR();
    rdA(0, 0, 1);
    if (st) stB(0, 0, 2 * (g + 1));
    BAR(); WLG0();
    PRIO1(); mma(1); PRIO0();
    BAR();
    rdB(0, 1); rdA(0, 1, 0);
    BAR(); WLG0();
    PRIO1(); mma(0); PRIO0();
    BAR();
    rdA(0, 1, 1);
    if (st) { stB(0, 1, 2 * (g + 1)); WVM6(); } else { WVM0(); }
    BAR(); WLG0();
    PRIO1(); mma(1); PRIO0();
    BAR();
    rdB(1, 0); rdA(1, 0, 0);
    if (st) { cvtxf(); wA(0, 0, xn0, xn1); }
    BAR(); WLG0();
    PRIO1(); mma(0); PRIO0();
    BAR();
    rdA(1, 0, 1);
    if (st) { bf16x8 w0, w1; chebw(2, w0, w1); wA(0, 1, w0, w1); }
    BAR(); WLG0();
    PRIO1(); mma(1); PRIO0();
    BAR();
    rdB(1, 1); rdA(1, 1, 0);
    if (st) { bf16x8 w0, w1; chebw(3, w0, w1); wA(1, 0, w0, w1); stB(1, 0, 2 * (g + 1) + 1); }
    BAR(); WLG0();
    PRIO1(); mma(0); PRIO0();
    BAR();
    rdA(1, 1, 1);
    if (st) { stB(1, 1, 2 * (g + 1) + 1); WVM4(); }
    BAR(); WLG0();
    PRIO1(); mma(1); PRIO0();
    BAR();
  }

  float bv[4] = {0.f, 0.f, 0.f, 0.f};
  const int c0 = n0 + wn * 64 + fr;
  if (bias) {
#pragma unroll
    for (int n = 0; n < 4; ++n) bv[n] = bias[c0 + n * 16];
  }
  float* Cz = C + (size_t)blockIdx.z * NR * NN;
  const int r0 = m0 + wm * 128 + kq * 4;
#pragma unroll
  for (int mi = 0; mi < 8; ++mi)
#pragma unroll
    for (int j = 0; j < 4; ++j) {
      float* p = Cz + (size_t)(r0 + mi * 16 + j) * NN + c0;
#pragma unroll
      for (int n = 0; n < 4; ++n)
        p[n * 16] = acc[mi][n][j] + bv[n];
    }
}

// out[row][c] = p0 + p1 + bias2[c]
__global__ __launch_bounds__(256) void k_reduce2(const float* __restrict__ p0,
                                                 const float* __restrict__ p1,
                                                 const float* __restrict__ bias,
                                                 float* __restrict__ out) {
  const size_t base = (size_t)blockIdx.x * 1024 + threadIdx.x * 4;
  const float4 a = *(const float4*)(p0 + base);
  const float4 b = *(const float4*)(p1 + base);
  const float4 c = *(const float4*)(bias + threadIdx.x * 4);
  float4 r;
  r.x = a.x + b.x + c.x;
  r.y = a.y + b.y + c.y;
  r.z = a.z + b.z + c.z;
  r.w = a.w + b.w + c.w;
  *(float4*)(out + base) = r;
}

// ---------------------------------------------------------------- launch

extern "C" void kernel_launch(void* const* d_in, const int* in_sizes, int n_in,
                              void* d_out, int out_size, void* d_ws, size_t ws_size,
                              hipStream_t stream) {
  const float* x         = (const float*)d_in[0];
  const float* coef_fc   = (const float*)d_in[1];
  const float* coef_proj = (const float*)d_in[2];
  const float* gamma     = (const float*)d_in[3];
  const float* beta      = (const float*)d_in[4];
  float* out = (float*)d_out;

  const size_t SZ_B   = (size_t)DIM_H * 4 * DIM_D * 2;   // 33.55 MB (each B)
  const size_t SZ_A1  = (size_t)NR * DIM_D * 4 * 2;      // 67.1 MB  (A1x / th)
  const size_t SZ_HB  = (size_t)NR * DIM_H * 2;          // 67.1 MB  (bf16 h)
  const size_t SZ_HF  = (size_t)NR * DIM_H * 4;          // 134.2 MB (fp32 h)
  const size_t SZ_A2  = (size_t)NR * DIM_H * 4 * 2;      // 268.4 MB (A2x)
  const size_t SZ_BP1 = (size_t)32 * DIM_H * 4;
  const size_t SZ_BP2 = (size_t)128 * DIM_D * 4;

  // fixed prefix: [B2p][bias1][bias2]
  char* w = (char*)d_ws;
  bf16*  B2p   = (bf16*)w;   w += SZ_B;
  float* bias1 = (float*)w;  w += DIM_H * 4;
  float* bias2 = (float*)w;  w += DIM_D * 4;
  char*  hbase = w;

  // PATH A: [h bf16 67.1][A2x 268.4 : {A1x 67.1 | B1p 33.6 | bpart 1.05 | ...}]
  // PATH B: [h fp32 134.2][A1x/th 67.1][B1p 33.6][bpart 1.05]
  const size_t NEED_A = (size_t)(hbase - (char*)d_ws) + SZ_HB + SZ_A2;
  const bool EXP = (ws_size >= NEED_A);

  char* region = hbase + (EXP ? SZ_HB : SZ_HF);
  bf16*  A1x    = (bf16*)region;
  bf16*  B1p    = (bf16*)(region + SZ_A1);
  float* bpart1 = (float*)(region + SZ_A1 + SZ_B);
  float* bpart2 = (float*)(region + SZ_A1 + SZ_B + SZ_BP1);

  // shared prep: permuted B + bias
  k_prep_t<DIM_D, DIM_H><<<dim3(DIM_H / 256, DIM_D / 32), 256, 0, stream>>>(coef_fc, B1p, bpart1);
  k_prep_t<DIM_H, DIM_D><<<dim3(DIM_D / 256, DIM_H / 32), 256, 0, stream>>>(coef_proj, B2p, bpart2);
  k_bias_red<<<DIM_H / 256, 256, 0, stream>>>(bpart1, bias1, DIM_H, DIM_D / 32);
  k_bias_red<<<DIM_D / 256, 256, 0, stream>>>(bpart2, bias2, DIM_D, DIM_H / 32);

  // expanded A1 = T_k(tanh(x)), K'-permuted
  k_tanh_cheb<<<NR * DIM_D / 2048, 256, 0, stream>>>(x, A1x);

  if (EXP) {
    bf16*  h    = (bf16*)hbase;
    bf16*  A2x  = (bf16*)region;                       // overlays A1x+B1p+bpart
    float* part = (float*)hbase;                       // overlays h (dead after lntanh)
    // GEMM1 pure: A1x * B1p -> h (bf16, +bias1)
    k_gemm8x<DIM_D, 1, bf16><<<dim3(DIM_H / 256, NR / 256, 1), 512, 0, stream>>>(
        A1x, B1p, h, bias1, DIM_H);
    k_lntanh_cheb<<<NR, 256, 0, stream>>>(h, gamma, beta, A2x);
    // GEMM2 pure: A2x * B2p -> partials (split-K x2)
    k_gemm8x<DIM_H, 2, float><<<dim3(DIM_D / 256, NR / 256, 2), 512, 0, stream>>>(
        A2x, B2p, part, nullptr, DIM_D);
    k_reduce2<<<NR, 256, 0, stream>>>(part, part + (size_t)NR * DIM_D, bias2, out);
  } else {
    float* h    = (float*)hbase;
    bf16*  th   = A1x;                                 // overlays A1x (dead after GEMM1)
    float* part = (float*)hbase;                       // overlays h (dead after ln_tanh)
    // GEMM1 pure: A1x * B1p -> h (fp32, +bias1)
    k_gemm8x<DIM_D, 1, float><<<dim3(DIM_H / 256, NR / 256, 1), 512, 0, stream>>>(
        A1x, B1p, h, bias1, DIM_H);
    k_ln_tanh<<<NR, 256, 0, stream>>>(h, gamma, beta, th);
    // GEMM2 fused (r5-proven): th * B2p -> partials (split-K x2)
    k_gemm8<DIM_H, 2><<<dim3(DIM_D / 256, NR / 256, 2), 512, 0, stream>>>(
        th, B2p, part, nullptr, DIM_D);
    k_reduce2<<<NR, 256, 0, stream>>>(part, part + (size_t)NR * DIM_D, bias2, out);
  }
}

// Round 7
// 687.467 us; speedup vs baseline: 1.1177x; 1.1177x over previous
//
#include <hip/hip_runtime.h>
#include <hip/hip_bf16.h>
#include <cstdint>
#include <cstddef>

typedef __bf16 bf16;
typedef __attribute__((ext_vector_type(4))) __bf16 bf16x4;
typedef __attribute__((ext_vector_type(8))) __bf16 bf16x8;
typedef __attribute__((ext_vector_type(4))) float f32x4;

#define NR 8192      // B*S rows
#define DIM_D 1024
#define DIM_H 4096

// ---------------------------------------------------------------- helpers

__device__ __forceinline__ void gload_lds16(const void* g, void* l) {
  __builtin_amdgcn_global_load_lds(
      (const __attribute__((address_space(1))) void*)g,
      (__attribute__((address_space(3))) void*)l, 16, 0, 0);
}

#define BAR()  __builtin_amdgcn_s_barrier()
#define WLG0() asm volatile("s_waitcnt lgkmcnt(0)" ::: "memory")
#define WVM0() asm volatile("s_waitcnt vmcnt(0)" ::: "memory")
#define WVM4() asm volatile("s_waitcnt vmcnt(4)" ::: "memory")
#define WVM6() asm volatile("s_waitcnt vmcnt(6)" ::: "memory")
#define WVM8() asm volatile("s_waitcnt vmcnt(8)" ::: "memory")
#define PRIO1() __builtin_amdgcn_s_setprio(1)
#define PRIO0() __builtin_amdgcn_s_setprio(0)

// ---------------------------------------------------------------- prep kernels

// Coalesced permuted-B prep. Block = (256 outputs) x (32 inputs = 1 chunk).
// Tile kt = chunk*2 + dp (dp=(k-1)>>1); elem (dh*4+q)*2048 + r*8 + j, dh=(k-1)&1,
// input i = chunk*32 + q*8 + j, r = o&255. bpart[chunk][o] = sum_i coef[i][o][0].
template <int IN, int OUT>
__global__ __launch_bounds__(256) void k_prep_t(const float* __restrict__ coef,
                                                bf16* __restrict__ Bp,
                                                float* __restrict__ bpart) {
  constexpr int KT = (IN / 32) * 2;
  const int tid   = threadIdx.x;
  const int o     = blockIdx.x * 256 + tid;
  const int nb    = blockIdx.x;
  const int chunk = blockIdx.y;
  const int i0    = chunk * 32;

  float bacc = 0.f;
#pragma unroll
  for (int q = 0; q < 4; ++q) {
    bf16x8 w1, w2, w3, w4;
#pragma unroll
    for (int j = 0; j < 8; ++j) {
      const float* s = coef + ((size_t)(i0 + q * 8 + j) * OUT + o) * 5;
      bacc += s[0];
      w1[j] = (bf16)s[1]; w2[j] = (bf16)s[2]; w3[j] = (bf16)s[3]; w4[j] = (bf16)s[4];
    }
    bf16* base = Bp + ((size_t)nb * KT + chunk * 2) * 16384 + (size_t)tid * 8;
    *(bf16x8*)(base + (0 * 4 + q) * 2048)         = w1;
    *(bf16x8*)(base + (1 * 4 + q) * 2048)         = w2;
    *(bf16x8*)(base + 16384 + (0 * 4 + q) * 2048) = w3;
    *(bf16x8*)(base + 16384 + (1 * 4 + q) * 2048) = w4;
  }
  bpart[(size_t)chunk * OUT + o] = bacc;
}

__global__ __launch_bounds__(256) void k_bias_red(const float* __restrict__ bpart,
                                                  float* __restrict__ bias,
                                                  const int OUT, const int NP) {
  const int o = blockIdx.x * 256 + threadIdx.x;
  float s = 0.f;
  for (int p = 0; p < NP; ++p) s += bpart[(size_t)p * OUT + o];
  bias[o] = s;
}

// A'1 tile prep, SAME tile format as B (so GEMM A-staging is coalesced):
// Ap[mb][kt=chunk*2+dp][(dh*4+q)*2048 + r*8 + j] = T_{dp*2+dh+1}(tanh(x[mb*256+r][chunk*32+q*8+j]))
// Writes: per (q,deg), 64 lanes x 16B consecutive = 1KB linear. Fully coalesced.
__global__ __launch_bounds__(256) void k_tanh_cheb_t(const float* __restrict__ x,
                                                     bf16* __restrict__ Ap) {
  const int mb    = blockIdx.x;
  const int chunk = blockIdx.y;
  const int r     = threadIdx.x;

  const float* src = x + (size_t)(mb * 256 + r) * DIM_D + chunk * 32;
  float a[32];
#pragma unroll
  for (int u = 0; u < 8; ++u) {
    const float4 v = *(const float4*)(src + u * 4);
    a[u * 4 + 0] = tanhf(v.x);
    a[u * 4 + 1] = tanhf(v.y);
    a[u * 4 + 2] = tanhf(v.z);
    a[u * 4 + 3] = tanhf(v.w);
  }
  bf16* base = Ap + ((size_t)mb * 64 + chunk * 2) * 16384 + (size_t)r * 8;
#pragma unroll
  for (int q = 0; q < 4; ++q) {
    bf16x8 w1, w2, w3, w4;
#pragma unroll
    for (int j = 0; j < 8; ++j) {
      const float t = a[q * 8 + j], t2 = t * t;
      w1[j] = (bf16)t;
      w2[j] = (bf16)(2.f * t2 - 1.f);
      w3[j] = (bf16)(t * (4.f * t2 - 3.f));
      w4[j] = (bf16)(8.f * t2 * (t2 - 1.f) + 1.f);
    }
    *(bf16x8*)(base + (0 * 4 + q) * 2048)         = w1;   // deg1: dp0 dh0
    *(bf16x8*)(base + (1 * 4 + q) * 2048)         = w2;   // deg2: dp0 dh1
    *(bf16x8*)(base + 16384 + (0 * 4 + q) * 2048) = w3;   // deg3: dp1 dh0
    *(bf16x8*)(base + 16384 + (1 * 4 + q) * 2048) = w4;   // deg4: dp1 dh1
  }
}

// LayerNorm + tanh, fp32 h -> bf16 th (row-major).
__global__ __launch_bounds__(256) void k_ln_tanh(const float* __restrict__ h,
                                                 const float* __restrict__ gamma,
                                                 const float* __restrict__ beta,
                                                 bf16* __restrict__ th) {
  const int n = blockIdx.x;
  const int t = threadIdx.x;
  const float* row = h + (size_t)n * DIM_H;

  float4 v[4];
  float s1 = 0.f, s2 = 0.f;
#pragma unroll
  for (int j = 0; j < 4; ++j) {
    v[j] = *(const float4*)(row + t * 16 + j * 4);
    s1 += v[j].x + v[j].y + v[j].z + v[j].w;
    s2 += v[j].x * v[j].x + v[j].y * v[j].y + v[j].z * v[j].z + v[j].w * v[j].w;
  }
#pragma unroll
  for (int off = 32; off >= 1; off >>= 1) {
    s1 += __shfl_xor(s1, off);
    s2 += __shfl_xor(s2, off);
  }
  __shared__ float red[8];
  if ((t & 63) == 0) { red[(t >> 6) * 2] = s1; red[(t >> 6) * 2 + 1] = s2; }
  __syncthreads();
  const float S1 = red[0] + red[2] + red[4] + red[6];
  const float S2 = red[1] + red[3] + red[5] + red[7];
  const float mu   = S1 * (1.f / DIM_H);
  const float var  = S2 * (1.f / DIM_H) - mu * mu;
  const float rstd = rsqrtf(var + 1e-5f);

  float tmp[16];
#pragma unroll
  for (int j = 0; j < 4; ++j) {
    const float4 g = *(const float4*)(gamma + t * 16 + j * 4);
    const float4 b = *(const float4*)(beta  + t * 16 + j * 4);
    tmp[j * 4 + 0] = tanhf((v[j].x - mu) * rstd * g.x + b.x);
    tmp[j * 4 + 1] = tanhf((v[j].y - mu) * rstd * g.y + b.y);
    tmp[j * 4 + 2] = tanhf((v[j].z - mu) * rstd * g.z + b.z);
    tmp[j * 4 + 3] = tanhf((v[j].w - mu) * rstd * g.w + b.w);
  }
  bf16x8 w0, w1;
#pragma unroll
  for (int j = 0; j < 8; ++j) { w0[j] = (bf16)tmp[j]; w1[j] = (bf16)tmp[8 + j]; }
  bf16* o = th + (size_t)n * DIM_H + t * 16;
  *(bf16x8*)o       = w0;
  *(bf16x8*)(o + 8) = w1;
}

// ---------------------------------------------------------------- pure 8-phase GEMM
// C = A' * Bp^T (+bias). Both operands pre-tiled; all staging via coalesced
// global_load_lds. 256x256, BK=64, 8 waves, counted vmcnt(6) at P4/P8.
// GX/GY: compile-time grid dims for the bijective XCD swizzle.
template <int IND, int NZ, int GX, typename CT>
__global__ __launch_bounds__(512, 2) void k_gemm8x(const bf16* __restrict__ Ap,
                                                   const bf16* __restrict__ Bp,
                                                   CT* __restrict__ C,
                                                   const float* __restrict__ bias,
                                                   const int NN) {
  constexpr int NCH = IND / 32 / NZ;
  constexpr int KTt = (IND / 32) * 2;
  constexpr int TOT = GX * 32 * NZ;
  constexpr int CPX = TOT / 8;

  __shared__ bf16 Ash[2][16384];
  __shared__ bf16 Bsh[2][16384];

  const int tid  = threadIdx.x;
  const int lane = tid & 63;
  const int wid  = tid >> 6;
  const int wm   = wid >> 2;
  const int wn   = wid & 3;
  const int fr   = lane & 15;
  const int kq   = lane >> 4;

  // bijective XCD swizzle
  int lin = blockIdx.x + GX * (blockIdx.y + 32 * blockIdx.z);
  lin = (lin & 7) * CPX + (lin >> 3);
  const int bx = lin % GX;
  const int by = (lin / GX) % 32;
  const int bz = lin / (GX * 32);

  const int m0  = by * 256;
  const int n0  = bx * 256;
  const int zc0 = bz * NCH;

  f32x4 acc[8][4];
#pragma unroll
  for (int m = 0; m < 8; ++m)
#pragma unroll
    for (int n = 0; n < 4; ++n) acc[m][n] = (f32x4){0.f, 0.f, 0.f, 0.f};

  const size_t bt0 = (size_t)bx * KTt + (size_t)zc0 * 2;
  const size_t at0 = (size_t)by * KTt + (size_t)zc0 * 2;

  auto stB = [&](int d, int kh, int ktl) {
    const bf16* s = Bp + (bt0 + (size_t)ktl) * 16384 + kh * 8192 + tid * 8;
    bf16* l = &Bsh[d][kh * 8192 + tid * 8];
    gload_lds16(s, l);
    gload_lds16(s + 4096, l + 4096);
  };
  auto stA = [&](int d, int kh, int ktl) {
    const bf16* s = Ap + (at0 + (size_t)ktl) * 16384 + kh * 8192 + tid * 8;
    bf16* l = &Ash[d][kh * 8192 + tid * 8];
    gload_lds16(s, l);
    gload_lds16(s + 4096, l + 4096);
  };

  bf16x8 afr[4], bfr[4];
  auto rdB = [&](int d, int kh) {
#pragma unroll
    for (int n = 0; n < 4; ++n)
      bfr[n] = *(const bf16x8*)&Bsh[d][(kh * 4 + kq) * 2048 + (wn * 64 + n * 16 + fr) * 8];
  };
  auto rdA = [&](int d, int kh, int mh) {
#pragma unroll
    for (int m = 0; m < 4; ++m)
      afr[m] = *(const bf16x8*)&Ash[d][(kh * 4 + kq) * 2048 + (wm * 128 + mh * 64 + m * 16 + fr) * 8];
  };
  auto mma = [&](int mh) {
#pragma unroll
    for (int m = 0; m < 4; ++m)
#pragma unroll
      for (int n = 0; n < 4; ++n)
        acc[mh * 4 + m][n] =
            __builtin_amdgcn_mfma_f32_16x16x32_bf16(afr[m], bfr[n], acc[mh * 4 + m][n], 0, 0, 0);
  };

  // prologue: tiles 0 (buf0) and 1 (buf1); drain tile 0 (8 newest stay).
  stA(0, 0, 0); stA(0, 1, 0); stB(0, 0, 0); stB(0, 1, 0);
  stA(1, 0, 1); stA(1, 1, 1); stB(1, 0, 1); stB(1, 1, 1);
  WVM8();
  BAR();

#pragma unroll 1
  for (int g = 0; g < NCH; ++g) {
    const bool st = (g + 1 < NCH);
    // P1: deferred A(buf1,kh1) for tile 2g+1
    rdB(0, 0); rdA(0, 0, 0);
    if (g > 0) stA(1, 1, 2 * g + 1);
    BAR(); WLG0();
    PRIO1(); mma(0); PRIO0();
    BAR();
    // P2
    rdA(0, 0, 1);
    if (st) stB(0, 0, 2 * g + 2);
    BAR(); WLG0();
    PRIO1(); mma(1); PRIO0();
    BAR();
    // P3
    rdB(0, 1); rdA(0, 1, 0);
    if (st) stA(0, 0, 2 * g + 2);
    BAR(); WLG0();
    PRIO1(); mma(0); PRIO0();
    BAR();
    // P4: tile 2g+1 fully staged after this wait
    rdA(0, 1, 1);
    if (st) { stB(0, 1, 2 * g + 2); WVM6(); } else { WVM0(); }
    BAR(); WLG0();
    PRIO1(); mma(1); PRIO0();
    BAR();
    // P5
    rdB(1, 0); rdA(1, 0, 0);
    if (st) stA(0, 1, 2 * g + 2);
    BAR(); WLG0();
    PRIO1(); mma(0); PRIO0();
    BAR();
    // P6
    rdA(1, 0, 1);
    if (st) stB(1, 0, 2 * g + 3);
    BAR(); WLG0();
    PRIO1(); mma(1); PRIO0();
    BAR();
    // P7
    rdB(1, 1); rdA(1, 1, 0);
    if (st) stA(1, 0, 2 * g + 3);
    BAR(); WLG0();
    PRIO1(); mma(0); PRIO0();
    BAR();
    // P8: tile 2g+2 fully staged after this wait
    rdA(1, 1, 1);
    if (st) { stB(1, 1, 2 * g + 3); WVM6(); }
    BAR(); WLG0();
    PRIO1(); mma(1); PRIO0();
    BAR();
  }

  // epilogue
  float bv[4] = {0.f, 0.f, 0.f, 0.f};
  const int c0 = n0 + wn * 64 + fr;
  if (bias) {
#pragma unroll
    for (int n = 0; n < 4; ++n) bv[n] = bias[c0 + n * 16];
  }
  CT* Cz = C + (size_t)bz * NR * NN;
  const int r0 = m0 + wm * 128 + kq * 4;
#pragma unroll
  for (int mi = 0; mi < 8; ++mi)
#pragma unroll
    for (int j = 0; j < 4; ++j) {
      CT* p = Cz + (size_t)(r0 + mi * 16 + j) * NN + c0;
#pragma unroll
      for (int n = 0; n < 4; ++n)
        p[n * 16] = (CT)(acc[mi][n][j] + bv[n]);
    }
}

// ---------------------------------------------------------------- fused GEMM (GEMM2)
// A generated in-kernel from th (cheb), staged with CONFLICT-FREE lane map:
// thread t -> row r=t&255, quarters q={qp,qp+1}, qp=(t>>8)*2. Writes linear.
template <int IND, int NZ, int GX>
__global__ __launch_bounds__(512, 2) void k_gemm8(const bf16* __restrict__ X,
                                                  const bf16* __restrict__ Bp,
                                                  float* __restrict__ C,
                                                  const float* __restrict__ bias,
                                                  const int NN) {
  constexpr int NCH = IND / 32 / NZ;
  constexpr int KTt = (IND / 32) * 2;
  constexpr int TOT = GX * 32 * NZ;
  constexpr int CPX = TOT / 8;

  __shared__ bf16 Ash[2][16384];
  __shared__ bf16 Bsh[2][16384];

  const int tid  = threadIdx.x;
  const int lane = tid & 63;
  const int wid  = tid >> 6;
  const int wm   = wid >> 2;
  const int wn   = wid & 3;
  const int fr   = lane & 15;
  const int kq   = lane >> 4;

  int lin = blockIdx.x + GX * (blockIdx.y + 32 * blockIdx.z);
  lin = (lin & 7) * CPX + (lin >> 3);
  const int bx = lin % GX;
  const int by = (lin / GX) % 32;
  const int bz = lin / (GX * 32);

  const int m0  = by * 256;
  const int n0  = bx * 256;
  const int zc0 = bz * NCH;

  const int rA = tid & 255;          // staging row
  const int qp = (tid >> 8) * 2;     // staging quarter base

  f32x4 acc[8][4];
#pragma unroll
  for (int m = 0; m < 8; ++m)
#pragma unroll
    for (int n = 0; n < 4; ++n) acc[m][n] = (f32x4){0.f, 0.f, 0.f, 0.f};

  const bf16* xp = X + (size_t)(m0 + rA) * IND + (size_t)zc0 * 32 + qp * 8;
  const size_t bt0 = (size_t)bx * KTt + (size_t)zc0 * 2;

  bf16x8 xn0, xn1;
  float  xf[16];
  bf16x8 afr[4], bfr[4];

  auto stB = [&](int d, int kh, int ktl) {
    const bf16* s = Bp + (bt0 + (size_t)ktl) * 16384 + kh * 8192 + tid * 8;
    bf16* l = &Bsh[d][kh * 8192 + tid * 8];
    gload_lds16(s, l);
    gload_lds16(s + 4096, l + 4096);
  };
  auto ldx = [&](int c) {
    const bf16* s = xp + (size_t)c * 32;
    xn0 = *(const bf16x8*)s;
    xn1 = *(const bf16x8*)(s + 8);
  };
  auto cvtxf = [&]() {
#pragma unroll
    for (int j = 0; j < 8; ++j) { xf[j] = (float)xn0[j]; xf[8 + j] = (float)xn1[j]; }
  };
  auto wA = [&](int d, int dh, bf16x8 w0, bf16x8 w1) {
    *(bf16x8*)&Ash[d][(dh * 4 + qp) * 2048 + rA * 8]     = w0;   // linear 1KB/wave
    *(bf16x8*)&Ash[d][(dh * 4 + qp + 1) * 2048 + rA * 8] = w1;
  };
  auto chebw = [&](int deg, bf16x8& w0, bf16x8& w1) {
#pragma unroll
    for (int j = 0; j < 8; ++j) {
      const float a = xf[j], b = xf[8 + j];
      const float a2 = a * a, b2 = b * b;
      float ra, rb;
      if (deg == 2)      { ra = 2.f * a2 - 1.f;            rb = 2.f * b2 - 1.f; }
      else if (deg == 3) { ra = a * (4.f * a2 - 3.f);      rb = b * (4.f * b2 - 3.f); }
      else               { ra = 8.f * a2 * (a2 - 1.f) + 1.f; rb = 8.f * b2 * (b2 - 1.f) + 1.f; }
      w0[j] = (bf16)ra; w1[j] = (bf16)rb;
    }
  };
  auto rdB = [&](int d, int kh) {
#pragma unroll
    for (int n = 0; n < 4; ++n)
      bfr[n] = *(const bf16x8*)&Bsh[d][(kh * 4 + kq) * 2048 + (wn * 64 + n * 16 + fr) * 8];
  };
  auto rdA = [&](int d, int kh, int mh) {
#pragma unroll
    for (int m = 0; m < 4; ++m)
      afr[m] = *(const bf16x8*)&Ash[d][(kh * 4 + kq) * 2048 + (wm * 128 + mh * 64 + m * 16 + fr) * 8];
  };
  auto mma = [&](int mh) {
#pragma unroll
    for (int m = 0; m < 4; ++m)
#pragma unroll
      for (int n = 0; n < 4; ++n)
        acc[mh * 4 + m][n] =
            __builtin_amdgcn_mfma_f32_16x16x32_bf16(afr[m], bfr[n], acc[mh * 4 + m][n], 0, 0, 0);
  };

  ldx(0);
  stB(0, 0, 0); stB(0, 1, 0);
  stB(1, 0, 1); stB(1, 1, 1);
  cvtxf();
  wA(0, 0, xn0, xn1);
  { bf16x8 w0, w1; chebw(2, w0, w1); wA(0, 1, w0, w1); }
  { bf16x8 w0, w1; chebw(3, w0, w1); wA(1, 0, w0, w1); }
  { bf16x8 w0, w1; chebw(4, w0, w1); wA(1, 1, w0, w1); }
  WVM0(); WLG0();
  BAR();

#pragma unroll 1
  for (int g = 0; g < NCH; ++g) {
    const bool st = (g + 1 < NCH);
    rdB(0, 0); rdA(0, 0, 0);
    if (g > 0) { bf16x8 w0, w1; chebw(4, w0, w1); wA(1, 1, w0, w1); }
    if (st) ldx(g + 1);
    BAR(); WLG0();
    PRIO1(); mma(0); PRIO0();
    BAR();
    rdA(0, 0, 1);
    if (st) stB(0, 0, 2 * (g + 1));
    BAR(); WLG0();
    PRIO1(); mma(1); PRIO0();
    BAR();
    rdB(0, 1); rdA(0, 1, 0);
    BAR(); WLG0();
    PRIO1(); mma(0); PRIO0();
    BAR();
    rdA(0, 1, 1);
    if (st) { stB(0, 1, 2 * (g + 1)); WVM6(); } else { WVM0(); }
    BAR(); WLG0();
    PRIO1(); mma(1); PRIO0();
    BAR();
    rdB(1, 0); rdA(1, 0, 0);
    if (st) { cvtxf(); wA(0, 0, xn0, xn1); }
    BAR(); WLG0();
    PRIO1(); mma(0); PRIO0();
    BAR();
    rdA(1, 0, 1);
    if (st) { bf16x8 w0, w1; chebw(2, w0, w1); wA(0, 1, w0, w1); }
    BAR(); WLG0();
    PRIO1(); mma(1); PRIO0();
    BAR();
    rdB(1, 1); rdA(1, 1, 0);
    if (st) { bf16x8 w0, w1; chebw(3, w0, w1); wA(1, 0, w0, w1); stB(1, 0, 2 * (g + 1) + 1); }
    BAR(); WLG0();
    PRIO1(); mma(0); PRIO0();
    BAR();
    rdA(1, 1, 1);
    if (st) { stB(1, 1, 2 * (g + 1) + 1); WVM4(); }
    BAR(); WLG0();
    PRIO1(); mma(1); PRIO0();
    BAR();
  }

  float bv[4] = {0.f, 0.f, 0.f, 0.f};
  const int c0 = n0 + wn * 64 + fr;
  if (bias) {
#pragma unroll
    for (int n = 0; n < 4; ++n) bv[n] = bias[c0 + n * 16];
  }
  float* Cz = C + (size_t)bz * NR * NN;
  const int r0 = m0 + wm * 128 + kq * 4;
#pragma unroll
  for (int mi = 0; mi < 8; ++mi)
#pragma unroll
    for (int j = 0; j < 4; ++j) {
      float* p = Cz + (size_t)(r0 + mi * 16 + j) * NN + c0;
#pragma unroll
      for (int n = 0; n < 4; ++n)
        p[n * 16] = acc[mi][n][j] + bv[n];
    }
}

// out[row][c] = p0 + p1 + bias2[c]
__global__ __launch_bounds__(256) void k_reduce2(const float* __restrict__ p0,
                                                 const float* __restrict__ p1,
                                                 const float* __restrict__ bias,
                                                 float* __restrict__ out) {
  const size_t base = (size_t)blockIdx.x * 1024 + threadIdx.x * 4;
  const float4 a = *(const float4*)(p0 + base);
  const float4 b = *(const float4*)(p1 + base);
  const float4 c = *(const float4*)(bias + threadIdx.x * 4);
  float4 r;
  r.x = a.x + b.x + c.x;
  r.y = a.y + b.y + c.y;
  r.z = a.z + b.z + c.z;
  r.w = a.w + b.w + c.w;
  *(float4*)(out + base) = r;
}

// ---------------------------------------------------------------- launch

extern "C" void kernel_launch(void* const* d_in, const int* in_sizes, int n_in,
                              void* d_out, int out_size, void* d_ws, size_t ws_size,
                              hipStream_t stream) {
  const float* x         = (const float*)d_in[0];
  const float* coef_fc   = (const float*)d_in[1];
  const float* coef_proj = (const float*)d_in[2];
  const float* gamma     = (const float*)d_in[3];
  const float* beta      = (const float*)d_in[4];
  float* out = (float*)d_out;

  const size_t SZ_B  = (size_t)DIM_H * 4 * DIM_D * 2;   // 33.55 MB each
  const size_t SZ_A1 = (size_t)NR * DIM_D * 4 * 2;      // 67.1 MB (A'1 tiles / th)
  const size_t SZ_HF = (size_t)NR * DIM_H * 4;          // 134.2 MB (fp32 h / partials)

  // layout (~270 MB, known-good ws >= ~301 MB):
  // [B2p][bias1][bias2][h fp32][A'1 -> th overlay][B1p][bpart1][bpart2]
  char* w = (char*)d_ws;
  bf16*  B2p   = (bf16*)w;   w += SZ_B;
  float* bias1 = (float*)w;  w += DIM_H * 4;
  float* bias2 = (float*)w;  w += DIM_D * 4;
  float* h     = (float*)w;  w += SZ_HF;
  bf16*  A1p   = (bf16*)w;   w += SZ_A1;
  bf16*  B1p   = (bf16*)w;   w += SZ_B;
  float* bpart1 = (float*)w; w += (size_t)32 * DIM_H * 4;
  float* bpart2 = (float*)w; w += (size_t)128 * DIM_D * 4;

  float* part = h;           // GEMM2 partials overlay h (dead after ln_tanh)
  bf16*  th   = A1p;         // th overlays A'1 (dead after GEMM1)

  // prep: permuted B tiles + bias folds
  k_prep_t<DIM_D, DIM_H><<<dim3(DIM_H / 256, DIM_D / 32), 256, 0, stream>>>(coef_fc, B1p, bpart1);
  k_prep_t<DIM_H, DIM_D><<<dim3(DIM_D / 256, DIM_H / 32), 256, 0, stream>>>(coef_proj, B2p, bpart2);
  k_bias_red<<<DIM_H / 256, 256, 0, stream>>>(bpart1, bias1, DIM_H, DIM_D / 32);
  k_bias_red<<<DIM_D / 256, 256, 0, stream>>>(bpart2, bias2, DIM_D, DIM_H / 32);

  // A'1 = T_k(tanh(x)) in B-mirrored tile format (coalesced GEMM staging)
  k_tanh_cheb_t<<<dim3(NR / 256, DIM_D / 32), 256, 0, stream>>>(x, A1p);

  // GEMM1 pure: A'1 * B1p -> h (fp32, +bias1)
  k_gemm8x<DIM_D, 1, 16, float><<<dim3(DIM_H / 256, NR / 256, 1), 512, 0, stream>>>(
      A1p, B1p, h, bias1, DIM_H);

  k_ln_tanh<<<NR, 256, 0, stream>>>(h, gamma, beta, th);

  // GEMM2 fused: th * B2p -> partials (split-K x2), then reduce(+bias2)
  k_gemm8<DIM_H, 2, 4><<<dim3(DIM_D / 256, NR / 256, 2), 512, 0, stream>>>(
      th, B2p, part, nullptr, DIM_D);
  k_reduce2<<<NR, 256, 0, stream>>>(part, part + (size_t)NR * DIM_D, bias2, out);
}

// Round 8
// 664.690 us; speedup vs baseline: 1.1560x; 1.0343x over previous
//
#include <hip/hip_runtime.h>
#include <hip/hip_bf16.h>
#include <cstdint>
#include <cstddef>

typedef __bf16 bf16;
typedef __attribute__((ext_vector_type(4))) __bf16 bf16x4;
typedef __attribute__((ext_vector_type(8))) __bf16 bf16x8;
typedef __attribute__((ext_vector_type(4))) float f32x4;

#define NR 8192      // B*S rows
#define DIM_D 1024
#define DIM_H 4096

// ---------------------------------------------------------------- helpers

__device__ __forceinline__ void gload_lds16(const void* g, void* l) {
  __builtin_amdgcn_global_load_lds(
      (const __attribute__((address_space(1))) void*)g,
      (__attribute__((address_space(3))) void*)l, 16, 0, 0);
}

#define BAR()  __builtin_amdgcn_s_barrier()
#define WVM0() asm volatile("s_waitcnt vmcnt(0)" ::: "memory")
#define WVM6() asm volatile("s_waitcnt vmcnt(6)" ::: "memory")
#define WVM8() asm volatile("s_waitcnt vmcnt(8)" ::: "memory")
#define PRIO1() __builtin_amdgcn_s_setprio(1)
#define PRIO0() __builtin_amdgcn_s_setprio(0)

// ---------------------------------------------------------------- prep kernels

// Coalesced permuted-B prep. Block = (256 outputs) x (32 inputs = 1 chunk).
// Tile kt = chunk*2 + dp (dp=(k-1)>>1); elem (dh*4+q)*2048 + r*8 + j, dh=(k-1)&1,
// input i = chunk*32 + q*8 + j, r = o&255. bpart[chunk][o] = sum_i coef[i][o][0].
template <int IN, int OUT>
__global__ __launch_bounds__(256) void k_prep_t(const float* __restrict__ coef,
                                                bf16* __restrict__ Bp,
                                                float* __restrict__ bpart) {
  constexpr int KT = (IN / 32) * 2;
  const int tid   = threadIdx.x;
  const int o     = blockIdx.x * 256 + tid;
  const int nb    = blockIdx.x;
  const int chunk = blockIdx.y;
  const int i0    = chunk * 32;

  float bacc = 0.f;
#pragma unroll
  for (int q = 0; q < 4; ++q) {
    bf16x8 w1, w2, w3, w4;
#pragma unroll
    for (int j = 0; j < 8; ++j) {
      const float* s = coef + ((size_t)(i0 + q * 8 + j) * OUT + o) * 5;
      bacc += s[0];
      w1[j] = (bf16)s[1]; w2[j] = (bf16)s[2]; w3[j] = (bf16)s[3]; w4[j] = (bf16)s[4];
    }
    bf16* base = Bp + ((size_t)nb * KT + chunk * 2) * 16384 + (size_t)tid * 8;
    *(bf16x8*)(base + (0 * 4 + q) * 2048)         = w1;
    *(bf16x8*)(base + (1 * 4 + q) * 2048)         = w2;
    *(bf16x8*)(base + 16384 + (0 * 4 + q) * 2048) = w3;
    *(bf16x8*)(base + 16384 + (1 * 4 + q) * 2048) = w4;
  }
  bpart[(size_t)chunk * OUT + o] = bacc;
}

__global__ __launch_bounds__(256) void k_bias_red(const float* __restrict__ bpart,
                                                  float* __restrict__ bias,
                                                  const int OUT, const int NP) {
  const int o = blockIdx.x * 256 + threadIdx.x;
  float s = 0.f;
  for (int p = 0; p < NP; ++p) s += bpart[(size_t)p * OUT + o];
  bias[o] = s;
}

// A'1 tile prep (B-mirrored tile format, coalesced writes).
__global__ __launch_bounds__(256) void k_tanh_cheb_t(const float* __restrict__ x,
                                                     bf16* __restrict__ Ap) {
  const int mb    = blockIdx.x;
  const int chunk = blockIdx.y;
  const int r     = threadIdx.x;

  const float* src = x + (size_t)(mb * 256 + r) * DIM_D + chunk * 32;
  float a[32];
#pragma unroll
  for (int u = 0; u < 8; ++u) {
    const float4 v = *(const float4*)(src + u * 4);
    a[u * 4 + 0] = tanhf(v.x);
    a[u * 4 + 1] = tanhf(v.y);
    a[u * 4 + 2] = tanhf(v.z);
    a[u * 4 + 3] = tanhf(v.w);
  }
  bf16* base = Ap + ((size_t)mb * 64 + chunk * 2) * 16384 + (size_t)r * 8;
#pragma unroll
  for (int q = 0; q < 4; ++q) {
    bf16x8 w1, w2, w3, w4;
#pragma unroll
    for (int j = 0; j < 8; ++j) {
      const float t = a[q * 8 + j], t2 = t * t;
      w1[j] = (bf16)t;
      w2[j] = (bf16)(2.f * t2 - 1.f);
      w3[j] = (bf16)(t * (4.f * t2 - 3.f));
      w4[j] = (bf16)(8.f * t2 * (t2 - 1.f) + 1.f);
    }
    *(bf16x8*)(base + (0 * 4 + q) * 2048)         = w1;
    *(bf16x8*)(base + (1 * 4 + q) * 2048)         = w2;
    *(bf16x8*)(base + 16384 + (0 * 4 + q) * 2048) = w3;
    *(bf16x8*)(base + 16384 + (1 * 4 + q) * 2048) = w4;
  }
}

// per-row LN stats from bf16 h: stats[row] = (mu, rstd)
__global__ __launch_bounds__(256) void k_ln_stats(const bf16* __restrict__ h,
                                                  float2* __restrict__ stats) {
  const int n = blockIdx.x;
  const int t = threadIdx.x;
  const bf16* row = h + (size_t)n * DIM_H;

  float s1 = 0.f, s2 = 0.f;
  {
    const bf16x8 a = *(const bf16x8*)(row + t * 16);
    const bf16x8 b = *(const bf16x8*)(row + t * 16 + 8);
#pragma unroll
    for (int j = 0; j < 8; ++j) {
      const float va = (float)a[j], vb = (float)b[j];
      s1 += va + vb;
      s2 += va * va + vb * vb;
    }
  }
#pragma unroll
  for (int off = 32; off >= 1; off >>= 1) {
    s1 += __shfl_xor(s1, off);
    s2 += __shfl_xor(s2, off);
  }
  __shared__ float red[8];
  if ((t & 63) == 0) { red[(t >> 6) * 2] = s1; red[(t >> 6) * 2 + 1] = s2; }
  __syncthreads();
  if (t == 0) {
    const float S1 = red[0] + red[2] + red[4] + red[6];
    const float S2 = red[1] + red[3] + red[5] + red[7];
    const float mu  = S1 * (1.f / DIM_H);
    const float var = S2 * (1.f / DIM_H) - mu * mu;
    stats[n] = make_float2(mu, rsqrtf(var + 1e-5f));
  }
}

// LN + tanh + cheb-expand into A'2 tiles (half-M panel of 4096 rows).
// Block = (mb_local, chunk); thread r owns row mb_local*256+r, 32 cols.
// Reads h rows (64B/lane, L2/L3-resident); writes fully coalesced tiles.
__global__ __launch_bounds__(256) void k_lntanh_cheb_t(const bf16* __restrict__ h,
                                                       const float2* __restrict__ stats,
                                                       const float* __restrict__ gamma,
                                                       const float* __restrict__ beta,
                                                       bf16* __restrict__ Ap) {
  const int mb    = blockIdx.x;        // 0..15 within half
  const int chunk = blockIdx.y;        // 0..127
  const int r     = threadIdx.x;
  const int row   = mb * 256 + r;      // local row in half

  const float2 st = stats[row];
  const bf16* src = h + (size_t)row * DIM_H + chunk * 32;

  float f[32];
#pragma unroll
  for (int q = 0; q < 4; ++q) {
    const bf16x8 v = *(const bf16x8*)(src + q * 8);
#pragma unroll
    for (int j = 0; j < 8; ++j) {
      const int c = chunk * 32 + q * 8 + j;
      f[q * 8 + j] = tanhf(((float)v[j] - st.x) * st.y * gamma[c] + beta[c]);
    }
  }
  bf16* base = Ap + ((size_t)mb * 256 + chunk * 2) * 16384 + (size_t)r * 8;
#pragma unroll
  for (int q = 0; q < 4; ++q) {
    bf16x8 w1, w2, w3, w4;
#pragma unroll
    for (int j = 0; j < 8; ++j) {
      const float t = f[q * 8 + j], t2 = t * t;
      w1[j] = (bf16)t;
      w2[j] = (bf16)(2.f * t2 - 1.f);
      w3[j] = (bf16)(t * (4.f * t2 - 3.f));
      w4[j] = (bf16)(8.f * t2 * (t2 - 1.f) + 1.f);
    }
    *(bf16x8*)(base + (0 * 4 + q) * 2048)         = w1;
    *(bf16x8*)(base + (1 * 4 + q) * 2048)         = w2;
    *(bf16x8*)(base + 16384 + (0 * 4 + q) * 2048) = w3;
    *(bf16x8*)(base + 16384 + (1 * 4 + q) * 2048) = w4;
  }
}

// ---------------------------------------------------------------- pure 8-phase GEMM
// C = A' * Bp^T (+bias). Both operands pre-tiled; coalesced global_load_lds
// staging; counted vmcnt(6) at P4/P8. NO explicit lgkmcnt fence: ds_reads are
// plain loads, the compiler emits fine-grained lgkmcnt interleaved with MFMA.
template <int IND, int NZ, int GX, int GY, typename CT>
__global__ __launch_bounds__(512, 2) void k_gemm8x(const bf16* __restrict__ Ap,
                                                   const bf16* __restrict__ Bp,
                                                   CT* __restrict__ C,
                                                   const float* __restrict__ bias,
                                                   const int NN, const int MR) {
  constexpr int NCH = IND / 32 / NZ;
  constexpr int KTt = (IND / 32) * 2;
  constexpr int TOT = GX * GY * NZ;
  constexpr int CPX = TOT / 8;

  __shared__ bf16 Ash[2][16384];
  __shared__ bf16 Bsh[2][16384];

  const int tid  = threadIdx.x;
  const int lane = tid & 63;
  const int wid  = tid >> 6;
  const int wm   = wid >> 2;
  const int wn   = wid & 3;
  const int fr   = lane & 15;
  const int kq   = lane >> 4;

  // bijective XCD swizzle
  int lin = blockIdx.x + GX * (blockIdx.y + GY * blockIdx.z);
  lin = (lin & 7) * CPX + (lin >> 3);
  const int bx = lin % GX;
  const int by = (lin / GX) % GY;
  const int bz = lin / (GX * GY);

  const int m0  = by * 256;
  const int n0  = bx * 256;
  const int zc0 = bz * NCH;

  f32x4 acc[8][4];
#pragma unroll
  for (int m = 0; m < 8; ++m)
#pragma unroll
    for (int n = 0; n < 4; ++n) acc[m][n] = (f32x4){0.f, 0.f, 0.f, 0.f};

  const size_t bt0 = (size_t)bx * KTt + (size_t)zc0 * 2;
  const size_t at0 = (size_t)by * KTt + (size_t)zc0 * 2;

  auto stB = [&](int d, int kh, int ktl) {
    const bf16* s = Bp + (bt0 + (size_t)ktl) * 16384 + kh * 8192 + tid * 8;
    bf16* l = &Bsh[d][kh * 8192 + tid * 8];
    gload_lds16(s, l);
    gload_lds16(s + 4096, l + 4096);
  };
  auto stA = [&](int d, int kh, int ktl) {
    const bf16* s = Ap + (at0 + (size_t)ktl) * 16384 + kh * 8192 + tid * 8;
    bf16* l = &Ash[d][kh * 8192 + tid * 8];
    gload_lds16(s, l);
    gload_lds16(s + 4096, l + 4096);
  };

  bf16x8 afr[4], bfr[4];
  auto rdB = [&](int d, int kh) {
#pragma unroll
    for (int n = 0; n < 4; ++n)
      bfr[n] = *(const bf16x8*)&Bsh[d][(kh * 4 + kq) * 2048 + (wn * 64 + n * 16 + fr) * 8];
  };
  auto rdA = [&](int d, int kh, int mh) {
#pragma unroll
    for (int m = 0; m < 4; ++m)
      afr[m] = *(const bf16x8*)&Ash[d][(kh * 4 + kq) * 2048 + (wm * 128 + mh * 64 + m * 16 + fr) * 8];
  };
  auto mma = [&](int mh) {
#pragma unroll
    for (int m = 0; m < 4; ++m)
#pragma unroll
      for (int n = 0; n < 4; ++n)
        acc[mh * 4 + m][n] =
            __builtin_amdgcn_mfma_f32_16x16x32_bf16(afr[m], bfr[n], acc[mh * 4 + m][n], 0, 0, 0);
  };

  // prologue: tiles 0 (buf0) and 1 (buf1); drain tile 0 (8 newest stay).
  stA(0, 0, 0); stA(0, 1, 0); stB(0, 0, 0); stB(0, 1, 0);
  stA(1, 0, 1); stA(1, 1, 1); stB(1, 0, 1); stB(1, 1, 1);
  WVM8();
  BAR();

#pragma unroll 1
  for (int g = 0; g < NCH; ++g) {
    const bool st = (g + 1 < NCH);
    // P1: deferred A(buf1,kh1) for tile 2g+1
    rdB(0, 0); rdA(0, 0, 0);
    if (g > 0) stA(1, 1, 2 * g + 1);
    BAR();
    PRIO1(); mma(0); PRIO0();
    BAR();
    // P2
    rdA(0, 0, 1);
    if (st) stB(0, 0, 2 * g + 2);
    BAR();
    PRIO1(); mma(1); PRIO0();
    BAR();
    // P3
    rdB(0, 1); rdA(0, 1, 0);
    if (st) stA(0, 0, 2 * g + 2);
    BAR();
    PRIO1(); mma(0); PRIO0();
    BAR();
    // P4: tile 2g+1 fully staged after this wait
    rdA(0, 1, 1);
    if (st) { stB(0, 1, 2 * g + 2); WVM6(); } else { WVM0(); }
    BAR();
    PRIO1(); mma(1); PRIO0();
    BAR();
    // P5
    rdB(1, 0); rdA(1, 0, 0);
    if (st) stA(0, 1, 2 * g + 2);
    BAR();
    PRIO1(); mma(0); PRIO0();
    BAR();
    // P6
    rdA(1, 0, 1);
    if (st) stB(1, 0, 2 * g + 3);
    BAR();
    PRIO1(); mma(1); PRIO0();
    BAR();
    // P7
    rdB(1, 1); rdA(1, 1, 0);
    if (st) stA(1, 0, 2 * g + 3);
    BAR();
    PRIO1(); mma(0); PRIO0();
    BAR();
    // P8: tile 2g+2 fully staged after this wait
    rdA(1, 1, 1);
    if (st) { stB(1, 1, 2 * g + 3); WVM6(); }
    BAR();
    PRIO1(); mma(1); PRIO0();
    BAR();
  }

  // epilogue
  float bv[4] = {0.f, 0.f, 0.f, 0.f};
  const int c0 = n0 + wn * 64 + fr;
  if (bias) {
#pragma unroll
    for (int n = 0; n < 4; ++n) bv[n] = bias[c0 + n * 16];
  }
  CT* Cz = C + (size_t)bz * MR * NN;
  const int r0 = m0 + wm * 128 + kq * 4;
#pragma unroll
  for (int mi = 0; mi < 8; ++mi)
#pragma unroll
    for (int j = 0; j < 4; ++j) {
      CT* p = Cz + (size_t)(r0 + mi * 16 + j) * NN + c0;
#pragma unroll
      for (int n = 0; n < 4; ++n)
        p[n * 16] = (CT)(acc[mi][n][j] + bv[n]);
    }
}

// out[row][c] = sum_z part[z][row][c] + bias2[c]; 4 bf16 partials -> fp32.
__global__ __launch_bounds__(256) void k_reduce4(const bf16* __restrict__ part,
                                                 const float* __restrict__ bias,
                                                 float* __restrict__ out) {
  const int row = blockIdx.x;                    // 0..4095 (local to half)
  const int c   = threadIdx.x * 4;
  const size_t base = (size_t)row * 1024 + c;
  float4 r = *(const float4*)(bias + c);
#pragma unroll
  for (int z = 0; z < 4; ++z) {
    const bf16x4 p = *(const bf16x4*)(part + (size_t)z * 4096 * 1024 + base);
    r.x += (float)p[0]; r.y += (float)p[1]; r.z += (float)p[2]; r.w += (float)p[3];
  }
  *(float4*)(out + base) = r;
}

// ---------------------------------------------------------------- launch

extern "C" void kernel_launch(void* const* d_in, const int* in_sizes, int n_in,
                              void* d_out, int out_size, void* d_ws, size_t ws_size,
                              hipStream_t stream) {
  const float* x         = (const float*)d_in[0];
  const float* coef_fc   = (const float*)d_in[1];
  const float* coef_proj = (const float*)d_in[2];
  const float* gamma     = (const float*)d_in[3];
  const float* beta      = (const float*)d_in[4];
  float* out = (float*)d_out;

  const size_t SZ_B   = (size_t)DIM_H * 4 * DIM_D * 2;       // 33.55 MB
  const size_t SZ_HB  = (size_t)NR * DIM_H * 2;              // 67.1 MB  (bf16 h)
  const size_t SZ_A2H = (size_t)(NR / 2) * DIM_H * 4 * 2;    // 134.2 MB (A'2 half tiles)
  const size_t SZ_A1  = (size_t)NR * DIM_D * 4 * 2;          // 67.1 MB  (A'1 tiles)
  const size_t SZ_PT  = (size_t)4 * (NR / 2) * DIM_D * 2;    // 33.55 MB (bf16 partials)

  // layout (~268.6 MB; known-good ws >= ~301.9 MB):
  // [B2p][bias1][bias2][stats][h bf16][R3: A'2half >= A'1+B1p+bparts][R4: partials]
  char* w = (char*)d_ws;
  bf16*   B2p   = (bf16*)w;    w += SZ_B;
  float*  bias1 = (float*)w;   w += DIM_H * 4;
  float*  bias2 = (float*)w;   w += DIM_D * 4;
  float2* stats = (float2*)w;  w += (size_t)NR * 8;
  bf16*   h     = (bf16*)w;    w += SZ_HB;
  char*   R3    = w;           w += SZ_A2H;
  bf16*   part  = (bf16*)w;    w += SZ_PT;

  bf16*  A1p    = (bf16*)R3;
  bf16*  B1p    = (bf16*)(R3 + SZ_A1);
  float* bpart1 = (float*)(R3 + SZ_A1 + SZ_B);
  float* bpart2 = (float*)(R3 + SZ_A1 + SZ_B + (size_t)32 * DIM_H * 4);
  bf16*  A2p    = (bf16*)R3;          // overlays A1p/B1p/bparts after GEMM1

  // prep: permuted B tiles + bias folds + A'1 tiles
  k_prep_t<DIM_D, DIM_H><<<dim3(DIM_H / 256, DIM_D / 32), 256, 0, stream>>>(coef_fc, B1p, bpart1);
  k_prep_t<DIM_H, DIM_D><<<dim3(DIM_D / 256, DIM_H / 32), 256, 0, stream>>>(coef_proj, B2p, bpart2);
  k_bias_red<<<DIM_H / 256, 256, 0, stream>>>(bpart1, bias1, DIM_H, DIM_D / 32);
  k_bias_red<<<DIM_D / 256, 256, 0, stream>>>(bpart2, bias2, DIM_D, DIM_H / 32);
  k_tanh_cheb_t<<<dim3(NR / 256, DIM_D / 32), 256, 0, stream>>>(x, A1p);

  // GEMM1 pure: A'1 * B1p -> h (bf16, +bias1)
  k_gemm8x<DIM_D, 1, 16, 32, bf16><<<dim3(16, 32, 1), 512, 0, stream>>>(
      A1p, B1p, h, bias1, DIM_H, NR);

  // LN stats (full 8192 rows)
  k_ln_stats<<<NR, 256, 0, stream>>>(h, stats);

  // GEMM2 in two M-halves: expand -> pure GEMM (split-K x4, bf16 partials) -> reduce
  for (int half = 0; half < 2; ++half) {
    const bf16*   hh = h + (size_t)half * (NR / 2) * DIM_H;
    const float2* sh = stats + (size_t)half * (NR / 2);
    k_lntanh_cheb_t<<<dim3(16, DIM_H / 32), 256, 0, stream>>>(hh, sh, gamma, beta, A2p);
    k_gemm8x<DIM_H, 4, 4, 16, bf16><<<dim3(4, 16, 4), 512, 0, stream>>>(
        A2p, B2p, part, nullptr, DIM_D, NR / 2);
    k_reduce4<<<NR / 2, 256, 0, stream>>>(part, bias2,
                                          out + (size_t)half * (NR / 2) * DIM_D);
  }
}